// Round 1
// baseline (1795.003 us; speedup 1.0000x reference)
//
#include <hip/hip_runtime.h>

// DistanceScaledDotAttention: B=4,H=8,S=2048,D=64
//   scores = (Q K^T / 8) * dist; masked -> -1e10; softmax; ctx = P V
//   outputs: ctx [4,8,2048,64] fp32, attn [4,8,2048,2048] fp32 (concat in d_out)
//
// Structure: one block = 8 q-rows of one (b,h). k-loop over 32 tiles of 64.
// QK^T and PV via v_mfma_f32_16x16x32_f16; unnormalized e=exp(s) kept in LDS
// (f16, 8x2048=32KB) so attn is written exactly once, normalized, at the end.
// No max-subtraction needed: |score| <= ~8 so exp() is safe in fp32.

typedef float v4f __attribute__((ext_vector_type(4)));
typedef _Float16 v8h __attribute__((ext_vector_type(8)));

#define SEQ 2048
#define DH  64
#define TQ  8
#define TK  64
#define NKT (SEQ / TK)   // 32
#define KPAD 72          // K/V tile row stride in halves (144B: 16B-aligned, 2-way banks)

__device__ inline v8h cvt8(float4 a, float4 b) {
    v8h h;
    h[0] = (_Float16)a.x; h[1] = (_Float16)a.y; h[2] = (_Float16)a.z; h[3] = (_Float16)a.w;
    h[4] = (_Float16)b.x; h[5] = (_Float16)b.y; h[6] = (_Float16)b.z; h[7] = (_Float16)b.w;
    return h;
}

__global__ __launch_bounds__(256, 3)
void dsda_kernel(const float* __restrict__ Qg, const float* __restrict__ Kg,
                 const float* __restrict__ Vg, const float* __restrict__ distg,
                 const int* __restrict__ maskg,
                 float* __restrict__ ctx_out, float* __restrict__ attn_out)
{
    const int bh   = blockIdx.x;    // 0..31  (b*8+h)  -- fast dim => spreads bh across XCDs
    const int qt   = blockIdx.y;    // 0..255
    const int q0   = qt * TQ;
    const int tid  = (int)threadIdx.x;
    const int wave = tid >> 6;      // 0..3
    const int lane = tid & 63;
    const int quad = lane >> 4;     // 0..3
    const int l16  = lane & 15;

    __shared__ __align__(16) _Float16 e_smem[TQ][SEQ];     // 32 KB, unnormalized exp(s)
    __shared__ __align__(16) _Float16 K_smem[TK][KPAD];    // 9216 B
    __shared__ __align__(16) _Float16 Vt_smem[DH][KPAD];   // 9216 B (transposed V tile)
    __shared__ float rs[TQ];                               // row sums

    if (tid < TQ) rs[tid] = 0.f;

    const size_t bh_off  = (size_t)bh * SEQ;
    const float* Qb = Qg + bh_off * DH;
    const float* Kb = Kg + bh_off * DH;
    const float* Vb = Vg + bh_off * DH;
    const size_t dm_base = (bh_off + (size_t)q0) * SEQ;    // dist/mask base for this q-tile

    // ---- Q A-fragments (persist whole kernel): A[m=l16][k=s*32+quad*8+j] ----
    v8h aq0 = {}, aq1 = {};
    if (l16 < TQ) {
        const float* qrow = Qb + (size_t)(q0 + l16) * DH;
        const float4* p0 = (const float4*)(qrow + quad * 8);
        const float4* p1 = (const float4*)(qrow + 32 + quad * 8);
        aq0 = cvt8(p0[0], p0[1]);
        aq1 = cvt8(p1[0], p1[1]);
    }

    v4f acc_pv = {0.f, 0.f, 0.f, 0.f};       // ctx accumulator: [row=quad*4+reg][d=wave*16+l16]
    float rsum[4] = {0.f, 0.f, 0.f, 0.f};    // per-lane row-sum partials (quad<2)

    const int r_st = tid >> 2;   // staging row 0..63
    const int c4   = tid & 3;    // staging col group 0..3 (16 floats each)

    for (int kt = 0; kt < NKT; ++kt) {
        __syncthreads();   // prior PV reads of K/Vt done before we overwrite
        const int k0 = kt * TK;

        // ---- issue K/V staging loads first (16 floats each) ----
        const float* krow = Kb + (size_t)(k0 + r_st) * DH + c4 * 16;
        const float* vrow = Vb + (size_t)(k0 + r_st) * DH + c4 * 16;
        float4 kv0 = ((const float4*)krow)[0];
        float4 kv1 = ((const float4*)krow)[1];
        float4 kv2 = ((const float4*)krow)[2];
        float4 kv3 = ((const float4*)krow)[3];
        float4 vv0 = ((const float4*)vrow)[0];
        float4 vv1 = ((const float4*)vrow)[1];
        float4 vv2 = ((const float4*)vrow)[2];
        float4 vv3 = ((const float4*)vrow)[3];

        // ---- then dist/mask for this tile (used after QK mfma -> latency hidden) ----
        float dv[4]; int mv[4];
        if (quad < 2) {
            const int kc = k0 + wave * 16 + l16;
#pragma unroll
            for (int r = 0; r < 4; ++r) {
                const size_t idx = dm_base + (size_t)(quad * 4 + r) * SEQ + kc;
                dv[r] = distg[idx];
                mv[r] = maskg[idx];
            }
        }

        // ---- convert + write LDS tiles ----
        *(v8h*)&K_smem[r_st][c4 * 16]     = cvt8(kv0, kv1);
        *(v8h*)&K_smem[r_st][c4 * 16 + 8] = cvt8(kv2, kv3);
        {
            const int db = c4 * 16;
            Vt_smem[db + 0][r_st] = (_Float16)vv0.x;  Vt_smem[db + 1][r_st] = (_Float16)vv0.y;
            Vt_smem[db + 2][r_st] = (_Float16)vv0.z;  Vt_smem[db + 3][r_st] = (_Float16)vv0.w;
            Vt_smem[db + 4][r_st] = (_Float16)vv1.x;  Vt_smem[db + 5][r_st] = (_Float16)vv1.y;
            Vt_smem[db + 6][r_st] = (_Float16)vv1.z;  Vt_smem[db + 7][r_st] = (_Float16)vv1.w;
            Vt_smem[db + 8][r_st] = (_Float16)vv2.x;  Vt_smem[db + 9][r_st] = (_Float16)vv2.y;
            Vt_smem[db +10][r_st] = (_Float16)vv2.z;  Vt_smem[db +11][r_st] = (_Float16)vv2.w;
            Vt_smem[db +12][r_st] = (_Float16)vv3.x;  Vt_smem[db +13][r_st] = (_Float16)vv3.y;
            Vt_smem[db +14][r_st] = (_Float16)vv3.z;  Vt_smem[db +15][r_st] = (_Float16)vv3.w;
        }
        __syncthreads();

        // ---- QK^T: wave w owns k-columns [k0+16w, +16). B[kk=quad*8+j][n=l16]=K[k0+16w+n][d] ----
        v8h bk0 = *(const v8h*)&K_smem[wave * 16 + l16][quad * 8];
        v8h bk1 = *(const v8h*)&K_smem[wave * 16 + l16][32 + quad * 8];
        v4f accs = {0.f, 0.f, 0.f, 0.f};
        accs = __builtin_amdgcn_mfma_f32_16x16x32_f16(aq0, bk0, accs, 0, 0, 0);
        accs = __builtin_amdgcn_mfma_f32_16x16x32_f16(aq1, bk1, accs, 0, 0, 0);

        // ---- epilogue: scale, mask, exp; stash e (f16) + row-sum partials ----
        if (quad < 2) {
            const int kc = k0 + wave * 16 + l16;
#pragma unroll
            for (int r = 0; r < 4; ++r) {
                const float sc = accs[r] * 0.125f * dv[r];
                const float e  = mv[r] ? 0.f : __expf(sc);
                rsum[r] += e;
                e_smem[quad * 4 + r][kc] = (_Float16)e;
            }
        }
        __syncthreads();

        // ---- PV: A[m=l16][kk]=e, B[kk][n=l16]=V[k0+kk][d=16w+n] via Vt ----
        v8h ap0 = {}, ap1 = {};
        if (l16 < TQ) {
            ap0 = *(const v8h*)&e_smem[l16][k0 + quad * 8];
            ap1 = *(const v8h*)&e_smem[l16][k0 + 32 + quad * 8];
        }
        v8h bv0 = *(const v8h*)&Vt_smem[wave * 16 + l16][quad * 8];
        v8h bv1 = *(const v8h*)&Vt_smem[wave * 16 + l16][32 + quad * 8];
        acc_pv = __builtin_amdgcn_mfma_f32_16x16x32_f16(ap0, bv0, acc_pv, 0, 0, 0);
        acc_pv = __builtin_amdgcn_mfma_f32_16x16x32_f16(ap1, bv1, acc_pv, 0, 0, 0);
    }

    // ---- reduce row sums: sum over l16 within quad, then across waves via LDS atomics ----
    if (quad < 2) {
#pragma unroll
        for (int r = 0; r < 4; ++r) {
            float v = rsum[r];
            v += __shfl_xor(v, 1);
            v += __shfl_xor(v, 2);
            v += __shfl_xor(v, 4);
            v += __shfl_xor(v, 8);
            if (l16 == 0) atomicAdd(&rs[quad * 4 + r], v);
        }
    }
    __syncthreads();

    // ---- context write: ctx[q0+row][16w+l16] = acc_pv[reg] / rs[row] ----
    if (quad < 2) {
#pragma unroll
        for (int r = 0; r < 4; ++r) {
            const int row = quad * 4 + r;
            const float inv = 1.f / rs[row];
            ctx_out[(bh_off + (size_t)(q0 + row)) * DH + wave * 16 + l16] = acc_pv[r] * inv;
        }
    }

    // ---- attn write: normalized e, coalesced float4 stores ----
    {
        const int r  = tid >> 5;        // 0..7
        const int tt = tid & 31;        // 0..31
        const float invr = 1.f / rs[r];
        float* arow = attn_out + dm_base + (size_t)r * SEQ;
#pragma unroll
        for (int c = 0; c < 8; ++c) {
            const int col = c * 256 + tt * 8;
            v8h e8 = *(const v8h*)&e_smem[r][col];
            float4 f0, f1;
            f0.x = (float)e8[0] * invr; f0.y = (float)e8[1] * invr;
            f0.z = (float)e8[2] * invr; f0.w = (float)e8[3] * invr;
            f1.x = (float)e8[4] * invr; f1.y = (float)e8[5] * invr;
            f1.z = (float)e8[6] * invr; f1.w = (float)e8[7] * invr;
            ((float4*)(arow + col))[0] = f0;
            ((float4*)(arow + col))[1] = f1;
        }
    }
}

extern "C" void kernel_launch(void* const* d_in, const int* in_sizes, int n_in,
                              void* d_out, int out_size, void* d_ws, size_t ws_size,
                              hipStream_t stream) {
    const float* Q    = (const float*)d_in[0];
    const float* K    = (const float*)d_in[1];
    const float* V    = (const float*)d_in[2];
    const float* dist = (const float*)d_in[3];
    const int*   mask = (const int*)d_in[4];

    float* ctx  = (float*)d_out;                                  // 4*8*2048*64
    float* attn = (float*)d_out + (size_t)4 * 8 * 2048 * 64;      // 4*8*2048*2048

    dim3 grid(32, SEQ / TQ);   // x = b*h (fast -> XCD spread), y = q-tile
    dim3 block(256);
    hipLaunchKernelGGL(dsda_kernel, grid, block, 0, stream,
                       Q, K, V, dist, mask, ctx, attn);
}